// Round 3
// baseline (430.843 us; speedup 1.0000x reference)
//
#include <hip/hip_runtime.h>

#define LQg 2048
#define LKg 2048
#define DDg 256
#define NBg 16
#define SMAX 4

typedef unsigned int uint;
typedef unsigned short ushort;
typedef __attribute__((ext_vector_type(8))) __bf16 bf16x8;
typedef __attribute__((ext_vector_type(16))) float f32x16;

static __device__ __forceinline__ uint pack2(float a, float b) {
    ushort ua = __builtin_bit_cast(ushort, (__bf16)a);
    ushort ub = __builtin_bit_cast(ushort, (__bf16)b);
    return (uint)ua | ((uint)ub << 16);
}

static __device__ __forceinline__ f32x16 mfma32(bf16x8 a, bf16x8 b, f32x16 c) {
    return __builtin_amdgcn_mfma_f32_32x32x16_bf16(a, b, c, 0, 0, 0);
}

static __device__ __forceinline__ int vrot(int dv) {
    return (((dv & 15) * 8) + (((dv >> 2) & 7) * 16)) & 127;
}

// ---- suffix-sum of V over [tile-aligned boundary, 2048) ----
__global__ void tv_partial_k(const float* __restrict__ V, const int* __restrict__ vlen,
                             float* __restrict__ part) {
    const int c = blockIdx.x, b = blockIdx.y, t = threadIdx.x;
    const int vl = vlen[b];
    int bnd = ((vl + 63) >> 6) << 6;
    if (bnd > LKg) bnd = LKg;
    const int k0 = c * 128, k1 = k0 + 128;
    int lo = k0 > bnd ? k0 : bnd;
    float s = 0.f;
    for (int k = lo; k < k1; ++k) s += V[((size_t)(b * LKg + k)) * DDg + t];
    part[(size_t)(b * 16 + c) * DDg + t] = s;
}

__global__ void tv_reduce_k(const float* __restrict__ part, float* __restrict__ TV) {
    const int b = blockIdx.x, t = threadIdx.x;
    float s = 0.f;
    for (int c = 0; c < 16; ++c) s += part[(size_t)(b * 16 + c) * DDg + t];
    TV[b * DDg + t] = s;
}

// ---- main fused attention: 4 waves, 128 q rows/block, KV split over blockIdx.y ----
__global__ __launch_bounds__(256, 2) void attn_k(
    const float* __restrict__ Qg, const float* __restrict__ Kg,
    const float* __restrict__ Vg, const int* __restrict__ vlen,
    const float* __restrict__ TV, float* __restrict__ Og,
    ushort* __restrict__ Pacc, float* __restrict__ Mp, float* __restrict__ Ep,
    int S, int use_tail) {
    __shared__ alignas(16) unsigned char sK[64 * 512];   // [64 k][256 d] bf16, XOR-swizzled
    __shared__ alignas(16) unsigned char sV[256 * 128];  // [256 dv][64 k] bf16, rotated rows

    const int tid = threadIdx.x;
    const int lane = tid & 63;
    const int w = tid >> 6;       // wave id 0..3
    const int lq = lane & 31;     // q row within wave tile
    const int h = lane >> 5;      // lane half
    const int b = blockIdx.x & 15;
    const int qb = blockIdx.x >> 4;   // 0..15 (128 q each)
    const int s = blockIdx.y;         // kv split
    const int q = qb * 128 + w * 32 + lq;
    const int vl = vlen[b];

    const float SCALE = 0.09016844136f;  // (1/sqrt(256)) * log2(e); exp2 domain

    const int nt = use_tail ? ((vl + 63) >> 6) : (LKg / 64);
    const int chunk = (nt + S - 1) / S;
    const int t0 = s * chunk;
    const int t1 = (t0 + chunk < nt) ? (t0 + chunk) : nt;

    if (S > 1 && t0 >= t1) {
        // empty split: record ell=0 and exit
        if (h == 0) {
            const size_t pidx = ((size_t)(s * NBg + b)) * LQg + q;
            Mp[pidx] = -1e30f;
            Ep[pidx] = 0.f;
        }
        return;
    }

    // ---- Q fragments in registers (pre-scaled, bf16) ----
    bf16x8 qf[16];
    {
        const float* qp = Qg + ((size_t)(b * LQg + q)) * DDg + h * 8;
#pragma unroll
        for (int c = 0; c < 16; ++c) {
            float4 a = *(const float4*)(qp + c * 16);
            float4 bb = *(const float4*)(qp + c * 16 + 4);
            uint4 u;
            u.x = pack2(a.x * SCALE, a.y * SCALE);
            u.y = pack2(a.z * SCALE, a.w * SCALE);
            u.z = pack2(bb.x * SCALE, bb.y * SCALE);
            u.w = pack2(bb.z * SCALE, bb.w * SCALE);
            qf[c] = __builtin_bit_cast(bf16x8, u);
        }
    }

    f32x16 acc[8];
#pragma unroll
    for (int i = 0; i < 8; ++i)
#pragma unroll
        for (int j = 0; j < 16; ++j) acc[i][j] = 0.f;

    float m = -1e30f, ell = 0.f;

    const int tt = tid & 63, th = tid >> 6;   // th 0..3
    const int swzK = (lq & 7) << 4;
    const int rotv = vrot(lq);

    for (int t = t0; t < t1; ++t) {
        const int k0 = t * 64;
        __syncthreads();

        // ---- stage K tile: [64][256] f32 -> bf16, XOR-swizzled rows ----
        {
            const float* kp = Kg + ((size_t)(b * LKg + k0)) * DDg;
#pragma unroll
            for (int i = 0; i < 16; ++i) {
                const int row = 4 * i + th;
                const int d4 = tt * 4;
                float4 v = *(const float4*)(kp + (size_t)row * DDg + d4);
                uint2 uu;
                uu.x = pack2(v.x, v.y);
                uu.y = pack2(v.z, v.w);
                const uint off = (uint)(row * 512) + (uint)((d4 * 2) ^ ((row & 7) << 4));
                *(uint2*)(sK + off) = uu;
            }
        }
        // ---- stage V tile transposed: [dv][k] bf16 with in-row rotation ----
        {
            const float* vp = Vg + ((size_t)(b * LKg + k0)) * DDg;
            const int dv4 = tt * 4;
#pragma unroll
            for (int kb = 0; kb < 4; ++kb) {
                const int kbase = th * 16 + kb * 4;
                float4 r0 = *(const float4*)(vp + (size_t)(kbase + 0) * DDg + dv4);
                float4 r1 = *(const float4*)(vp + (size_t)(kbase + 1) * DDg + dv4);
                float4 r2 = *(const float4*)(vp + (size_t)(kbase + 2) * DDg + dv4);
                float4 r3 = *(const float4*)(vp + (size_t)(kbase + 3) * DDg + dv4);
                {
                    const int dv = dv4 + 0;
                    uint2 uu; uu.x = pack2(r0.x, r1.x); uu.y = pack2(r2.x, r3.x);
                    *(uint2*)(sV + (uint)(dv * 128) + (uint)((kbase * 2 + vrot(dv)) & 127)) = uu;
                }
                {
                    const int dv = dv4 + 1;
                    uint2 uu; uu.x = pack2(r0.y, r1.y); uu.y = pack2(r2.y, r3.y);
                    *(uint2*)(sV + (uint)(dv * 128) + (uint)((kbase * 2 + vrot(dv)) & 127)) = uu;
                }
                {
                    const int dv = dv4 + 2;
                    uint2 uu; uu.x = pack2(r0.z, r1.z); uu.y = pack2(r2.z, r3.z);
                    *(uint2*)(sV + (uint)(dv * 128) + (uint)((kbase * 2 + vrot(dv)) & 127)) = uu;
                }
                {
                    const int dv = dv4 + 3;
                    uint2 uu; uu.x = pack2(r0.w, r1.w); uu.y = pack2(r2.w, r3.w);
                    *(uint2*)(sV + (uint)(dv * 128) + (uint)((kbase * 2 + vrot(dv)) & 127)) = uu;
                }
            }
        }
        __syncthreads();

        // ---- QK^T as S^T = mfma(K, Q^T): pair (l, l+32) holds P-row for q ----
        f32x16 s0, s1;
#pragma unroll
        for (int j = 0; j < 16; ++j) { s0[j] = 0.f; s1[j] = 0.f; }
#pragma unroll
        for (int c = 0; c < 16; ++c) {
            const int inner = (c * 32 + h * 16) ^ swzK;
            bf16x8 kf0 = *(const bf16x8*)(sK + lq * 512 + inner);
            bf16x8 kf1 = *(const bf16x8*)(sK + (32 + lq) * 512 + inner);
            s0 = mfma32(kf0, qf[c], s0);
            s1 = mfma32(kf1, qf[c], s1);
        }

        // ---- mask (masked score := 0, matching the reference) ----
        const bool full = (k0 + 64 <= vl);
        if (!full) {
            const int kb0 = k0 + 4 * h;
#pragma unroll
            for (int r = 0; r < 16; ++r) {
                const int key0 = kb0 + (r & 3) + 8 * (r >> 2);
                if (key0 >= vl) s0[r] = 0.f;
                if (key0 + 32 >= vl) s1[r] = 0.f;
            }
        }

        // ---- online softmax; pair-consistent m/ell ----
        float mt = s0[0];
#pragma unroll
        for (int r = 1; r < 16; ++r) mt = fmaxf(mt, s0[r]);
#pragma unroll
        for (int r = 0; r < 16; ++r) mt = fmaxf(mt, s1[r]);
        mt = fmaxf(mt, __shfl_xor(mt, 32));
        if (mt > m + 8.f) {
            const float mn = fmaxf(m, mt);
            const float sf = exp2f(m - mn);
            ell *= sf;
#pragma unroll
            for (int i = 0; i < 8; ++i) acc[i] *= sf;
            m = mn;
        }
        float rs = 0.f;
#pragma unroll
        for (int r = 0; r < 16; ++r) { s0[r] = exp2f(s0[r] - m); rs += s0[r]; }
#pragma unroll
        for (int r = 0; r < 16; ++r) { s1[r] = exp2f(s1[r] - m); rs += s1[r]; }
        rs += __shfl_xor(rs, 32);
        ell += rs;

        // ---- build P^T B-fragments (half-exchange via shfl_xor 32) ----
        bf16x8 pf[4];
#pragma unroll
        for (int kc = 0; kc < 4; ++kc) {
            const f32x16& ps = (kc < 2) ? s0 : s1;
            const int bb = (kc & 1) * 8;
            uint w0 = pack2(ps[bb + 0], ps[bb + 1]);
            uint w1 = pack2(ps[bb + 2], ps[bb + 3]);
            uint w2 = pack2(ps[bb + 4], ps[bb + 5]);
            uint w3 = pack2(ps[bb + 6], ps[bb + 7]);
            uint e0 = __shfl_xor(w0, 32);
            uint e1 = __shfl_xor(w1, 32);
            uint e2 = __shfl_xor(w2, 32);
            uint e3 = __shfl_xor(w3, 32);
            uint4 u;
            u.x = h ? e2 : w0;
            u.y = h ? e3 : w1;
            u.z = h ? w2 : e0;
            u.w = h ? w3 : e1;
            pf[kc] = __builtin_bit_cast(bf16x8, u);
        }

        // ---- PV: O^T += mfma(V^T, P^T) ----
#pragma unroll
        for (int kc = 0; kc < 4; ++kc) {
            const int kk = kc * 16 + h * 8;
            const int o0 = (kk * 2 + rotv) & 127;
            const int o1 = ((kk + 4) * 2 + rotv) & 127;
#pragma unroll
            for (int dt = 0; dt < 8; ++dt) {
                const uint base = (uint)(dt * 4096 + lq * 128);
                uint2 a = *(const uint2*)(sV + base + (uint)o0);
                uint2 c2 = *(const uint2*)(sV + base + (uint)o1);
                uint4 u; u.x = a.x; u.y = a.y; u.z = c2.x; u.w = c2.y;
                acc[dt] = mfma32(__builtin_bit_cast(bf16x8, u), pf[kc], acc[dt]);
            }
        }
    }

    if (S > 1) {
        // ---- write partial (m, ell, bf16 acc); combine applies tail + divide ----
        const size_t pidx = ((size_t)(s * NBg + b)) * LQg + q;
        if (h == 0) { Mp[pidx] = m; Ep[pidx] = ell; }
        ushort* pp = Pacc + pidx * DDg;
#pragma unroll
        for (int dt = 0; dt < 8; ++dt) {
#pragma unroll
            for (int rg = 0; rg < 4; ++rg) {
                const int dv0 = dt * 32 + 8 * rg + 4 * h;
                uint2 uu;
                uu.x = pack2(acc[dt][rg * 4 + 0], acc[dt][rg * 4 + 1]);
                uu.y = pack2(acc[dt][rg * 4 + 2], acc[dt][rg * 4 + 3]);
                *(uint2*)(pp + dv0) = uu;
            }
        }
        return;
    }

    // ---- S==1: analytic masked tail + divide, direct out ----
    if (use_tail) {
        const int bnd = nt * 64;
        const int cnt = LKg - bnd;
        if (cnt > 0) {
            if (m < -8.f) {
                const float sf = exp2f(m);
                ell *= sf;
#pragma unroll
                for (int i = 0; i < 8; ++i) acc[i] *= sf;
                m = 0.f;
            }
            const float pt = exp2f(-m);
            ell += (float)cnt * pt;
            const float* tp = TV + b * DDg + h * 4;
#pragma unroll
            for (int dt = 0; dt < 8; ++dt) {
#pragma unroll
                for (int rg = 0; rg < 4; ++rg) {
                    float4 tv = *(const float4*)(tp + dt * 32 + rg * 8);
                    acc[dt][rg * 4 + 0] += pt * tv.x;
                    acc[dt][rg * 4 + 1] += pt * tv.y;
                    acc[dt][rg * 4 + 2] += pt * tv.z;
                    acc[dt][rg * 4 + 3] += pt * tv.w;
                }
            }
        }
    }
    const float inv = 1.f / ell;
    float* op = Og + ((size_t)(b * LQg + q)) * DDg + h * 4;
#pragma unroll
    for (int dt = 0; dt < 8; ++dt) {
#pragma unroll
        for (int rg = 0; rg < 4; ++rg) {
            float4 o;
            o.x = acc[dt][rg * 4 + 0] * inv;
            o.y = acc[dt][rg * 4 + 1] * inv;
            o.z = acc[dt][rg * 4 + 2] * inv;
            o.w = acc[dt][rg * 4 + 3] * inv;
            *(float4*)(op + dt * 32 + rg * 8) = o;
        }
    }
}

// ---- combine splits + analytic tail + divide ----
__global__ void combine_k(const ushort* __restrict__ Pacc, const float* __restrict__ Mp,
                          const float* __restrict__ Ep, const float* __restrict__ TV,
                          const int* __restrict__ vlen, float* __restrict__ Og, int S) {
    const int t = threadIdx.x;
    const int qi = t >> 6;          // 0..3
    const int dv4 = (t & 63) * 4;
    const long long bq0 = (long long)blockIdx.x * 4;
    const int b = (int)(bq0 >> 11);
    const int q = (int)(bq0 & 2047) + qi;
    const int vl = vlen[b];
    int bnd = ((vl + 63) >> 6) << 6;
    if (bnd > LKg) bnd = LKg;
    const int cnt = LKg - bnd;

    float mi[SMAX], ei[SMAX];
    float M = (cnt > 0) ? 0.f : -1e30f;
    for (int s = 0; s < S; ++s) {
        const size_t pidx = ((size_t)(s * NBg + b)) * LQg + q;
        mi[s] = Mp[pidx];
        ei[s] = Ep[pidx];
        if (ei[s] > 0.f) M = fmaxf(M, mi[s]);
    }
    float L = 0.f;
    float o0 = 0.f, o1 = 0.f, o2 = 0.f, o3 = 0.f;
    for (int s = 0; s < S; ++s) {
        if (ei[s] > 0.f) {
            const float wg = exp2f(mi[s] - M);
            L += ei[s] * wg;
            const size_t pidx = ((size_t)(s * NBg + b)) * LQg + q;
            uint2 uu = *(const uint2*)(Pacc + pidx * DDg + dv4);
            o0 += wg * __builtin_bit_cast(float, (uu.x & 0xFFFFu) << 16);
            o1 += wg * __builtin_bit_cast(float, (uu.x & 0xFFFF0000u));
            o2 += wg * __builtin_bit_cast(float, (uu.y & 0xFFFFu) << 16);
            o3 += wg * __builtin_bit_cast(float, (uu.y & 0xFFFF0000u));
        }
    }
    if (cnt > 0) {
        const float pt = exp2f(-M);
        L += (float)cnt * pt;
        float4 tv = *(const float4*)(TV + b * DDg + dv4);
        o0 += pt * tv.x; o1 += pt * tv.y; o2 += pt * tv.z; o3 += pt * tv.w;
    }
    const float inv = 1.f / L;
    float4 o; o.x = o0 * inv; o.y = o1 * inv; o.z = o2 * inv; o.w = o3 * inv;
    *(float4*)(Og + ((size_t)(b * LQg + q)) * DDg + dv4) = o;
}

extern "C" void kernel_launch(void* const* d_in, const int* in_sizes, int n_in,
                              void* d_out, int out_size, void* d_ws, size_t ws_size,
                              hipStream_t stream) {
    const float* Q = (const float*)d_in[0];
    const float* K = (const float*)d_in[1];
    const float* V = (const float*)d_in[2];
    const int* vlen = (const int*)d_in[3];
    float* out = (float*)d_out;

    // workspace layout
    const size_t off_part = 0;                            // 16*16*256*4   = 256 KB
    const size_t off_TV = off_part + (size_t)NBg * 16 * DDg * 4;
    const size_t off_M = off_TV + (size_t)NBg * DDg * 4;  // SMAX*16*2048*4 = 512 KB
    const size_t off_E = off_M + (size_t)SMAX * NBg * LQg * 4;
    const size_t off_acc = off_E + (size_t)SMAX * NBg * LQg * 4;
    const size_t acc_per_split = (size_t)NBg * LQg * DDg * 2;  // 16 MB

    int S = 1, use_tail = 0;
    if (ws_size >= off_acc + 4 * acc_per_split) { S = 4; use_tail = 1; }
    else if (ws_size >= off_acc + 2 * acc_per_split) { S = 2; use_tail = 1; }
    else if (ws_size >= off_M) { S = 1; use_tail = 1; }

    float* part = (float*)((char*)d_ws + off_part);
    float* TV = (float*)((char*)d_ws + off_TV);
    float* Mp = (float*)((char*)d_ws + off_M);
    float* Ep = (float*)((char*)d_ws + off_E);
    ushort* Pacc = (ushort*)((char*)d_ws + off_acc);

    if (use_tail) {
        tv_partial_k<<<dim3(16, 16), 256, 0, stream>>>(V, vlen, part);
        tv_reduce_k<<<dim3(16), 256, 0, stream>>>(part, TV);
    }
    attn_k<<<dim3(256, S), dim3(256), 0, stream>>>(Q, K, V, vlen, TV, out,
                                                   Pacc, Mp, Ep, S, use_tail);
    if (S > 1) {
        combine_k<<<dim3(NBg * LQg / 4), dim3(256), 0, stream>>>(Pacc, Mp, Ep, TV, vlen, out, S);
    }
}

// Round 5
// 203.613 us; speedup vs baseline: 2.1160x; 2.1160x over previous
//
#include <hip/hip_runtime.h>

#define LQg 2048
#define LKg 2048
#define DDg 256
#define NBg 16
#define KVB 32
#define NTILES 64   // LKg / KVB

typedef unsigned int uint;
typedef unsigned short ushort;
typedef unsigned char uchar;
typedef __attribute__((ext_vector_type(8))) __bf16 bf16x8;
typedef __attribute__((ext_vector_type(16))) float f32x16;

static __device__ __forceinline__ uint pack2(float a, float b) {
    ushort ua = __builtin_bit_cast(ushort, (__bf16)a);
    ushort ub = __builtin_bit_cast(ushort, (__bf16)b);
    return (uint)ua | ((uint)ub << 16);
}

static __device__ __forceinline__ f32x16 mfma32(bf16x8 a, bf16x8 b, f32x16 c) {
    return __builtin_amdgcn_mfma_f32_32x32x16_bf16(a, b, c, 0, 0, 0);
}

// async global->LDS, 16B per lane; dest must be wave-uniform base + lane*16
typedef const __attribute__((address_space(1))) uchar* gas_t;
typedef __attribute__((address_space(3))) uchar* las_t;
static __device__ __forceinline__ void gl_lds16(const void* g, void* l) {
    __builtin_amdgcn_global_load_lds((gas_t)g, (las_t)l, 16, 0, 0);
}

// ---------------- prep: K -> bf16 LDS-image (rows 512B, 16B-chunk XOR swizzle) ----
__global__ __launch_bounds__(256) void prep_k(const float* __restrict__ K,
                                              uchar* __restrict__ Kimg) {
    const uint gid = blockIdx.x * 256 + threadIdx.x;   // one 16B chunk (8 d-elems)
    const uint d8 = gid & 31;          // chunk within row (256 d / 8)
    const uint row = (gid >> 5) & 31;  // key within tile
    const uint t = (gid >> 10) & 63;
    const uint b = gid >> 16;
    const float* src = K + (((size_t)b * LKg + t * KVB + row) * DDg + d8 * 8);
    float4 a = *(const float4*)src;
    float4 c = *(const float4*)(src + 4);
    uint4 u;
    u.x = pack2(a.x, a.y); u.y = pack2(a.z, a.w);
    u.z = pack2(c.x, c.y); u.w = pack2(c.z, c.w);
    const size_t base = ((size_t)(b * NTILES + t)) << 14;
    const uint off = row * 512 + ((d8 * 16) ^ ((row & 7) << 4));
    *(uint4*)(Kimg + base + off) = u;
}

// ---------------- prep: V -> bf16 transposed image [dv][32k*2B], dword-rotated ----
// k-pair p (k=2p,2p+1) of row dv lives at byte (4p + rot(dv)) & 63, rot = 4*((dv>>1)&15).
__global__ __launch_bounds__(256) void prep_v(const float* __restrict__ V,
                                              uchar* __restrict__ Vimg) {
    const uint gid = blockIdx.x * 256 + threadIdx.x;   // one dv-row of one tile
    const uint dv = gid & 255;
    const uint t = (gid >> 8) & 63;
    const uint b = gid >> 14;
    const uint rot = 4 * ((dv >> 1) & 15);
    uchar* base = Vimg + (((size_t)(b * NTILES + t)) << 14) + dv * 64;
    const float* src = V + ((size_t)b * LKg + t * KVB) * DDg + dv;
#pragma unroll
    for (int kq = 0; kq < 8; ++kq) {
        float v0 = src[(kq * 4 + 0) * DDg];
        float v1 = src[(kq * 4 + 1) * DDg];
        float v2 = src[(kq * 4 + 2) * DDg];
        float v3 = src[(kq * 4 + 3) * DDg];
        const uint o = (8 * kq + rot) & 63;
        *(uint*)(base + o) = pack2(v0, v1);
        *(uint*)(base + ((o + 4) & 63)) = pack2(v2, v3);
    }
}

// ---------------- suffix-sum of V over [32-aligned boundary, 2048) ----------------
__global__ void tv_partial_k(const float* __restrict__ V, const int* __restrict__ vlen,
                             float* __restrict__ part) {
    const int c = blockIdx.x, b = blockIdx.y, t = threadIdx.x;
    const int vl = vlen[b];
    int bnd = ((vl + 31) >> 5) << 5;
    if (bnd > LKg) bnd = LKg;
    const int k0 = c * 128, k1 = k0 + 128;
    int lo = k0 > bnd ? k0 : bnd;
    float s = 0.f;
    for (int k = lo; k < k1; ++k) s += V[((size_t)(b * LKg + k)) * DDg + t];
    part[(size_t)(b * 16 + c) * DDg + t] = s;
}

__global__ void tv_reduce_k(const float* __restrict__ part, float* __restrict__ TV) {
    const int b = blockIdx.x, t = threadIdx.x;
    float s = 0.f;
    for (int c = 0; c < 16; ++c) s += part[(size_t)(b * 16 + c) * DDg + t];
    TV[b * DDg + t] = s;
}

// ---------------- main fused attention: 2 waves, 64 q/block, dbuf prefetch -------
template <int IMG>
__global__ __launch_bounds__(128, 1) void attn_k(
    const float* __restrict__ Qg, const float* __restrict__ Kg,
    const float* __restrict__ Vg, const uchar* __restrict__ Kimg,
    const uchar* __restrict__ Vimg, const int* __restrict__ vlen,
    const float* __restrict__ TV, float* __restrict__ Og, int use_tail) {
    __shared__ alignas(16) uchar sK[2][KVB * 512];   // 2 x 16 KB
    __shared__ alignas(16) uchar sV[2][256 * 64];    // 2 x 16 KB

    const int tid = threadIdx.x;
    const int lane = tid & 63;
    const int w = tid >> 6;
    const int lq = lane & 31;
    const int h = lane >> 5;
    const int b = blockIdx.x >> 5;     // qb-inner ordering for XCD L2 reuse
    const int qb = blockIdx.x & 31;
    const int q = qb * 64 + w * 32 + lq;
    const int vl = vlen[b];

    const float SCALE = 0.09016844136f;  // (1/sqrt(256)) * log2(e)

    const int nt = use_tail ? ((vl + KVB - 1) / KVB) : NTILES;
    const int swzK = (lq & 7) << 4;
    const int rotv = (lq >> 1) * 4;

    // ---- prologue: stage tile 0 ----
    int cur = 0;
    if (nt > 0) {
        if (IMG) {
            const uchar* gK = Kimg + (((size_t)(b * NTILES + 0)) << 14) + tid * 16;
            const uchar* gV = Vimg + (((size_t)(b * NTILES + 0)) << 14) + tid * 16;
#pragma unroll
            for (int i = 0; i < 8; ++i) {
                gl_lds16(gK + i * 2048, &sK[0][i * 2048 + tid * 16]);
                gl_lds16(gV + i * 2048, &sV[0][i * 2048 + tid * 16]);
            }
        }
    }

    // ---- Q fragments (overlaps staging latency) ----
    bf16x8 qf[16];
    {
        const float* qp = Qg + ((size_t)(b * LQg + q)) * DDg + h * 8;
#pragma unroll
        for (int c = 0; c < 16; ++c) {
            float4 a = *(const float4*)(qp + c * 16);
            float4 bb = *(const float4*)(qp + c * 16 + 4);
            uint4 u;
            u.x = pack2(a.x * SCALE, a.y * SCALE);
            u.y = pack2(a.z * SCALE, a.w * SCALE);
            u.z = pack2(bb.x * SCALE, bb.y * SCALE);
            u.w = pack2(bb.z * SCALE, bb.w * SCALE);
            qf[c] = __builtin_bit_cast(bf16x8, u);
        }
    }

    // non-image staging (fallback path), tile 0
    if (!IMG && nt > 0) {
#pragma unroll
        for (int i = 0; i < 8; ++i) {
            const int cid = i * 128 + tid;
            const int d8 = cid & 31, row = cid >> 5;
            const float* src = Kg + (((size_t)b * LKg + row) * DDg + d8 * 8);
            float4 a = *(const float4*)src;
            float4 c = *(const float4*)(src + 4);
            uint4 u;
            u.x = pack2(a.x, a.y); u.y = pack2(a.z, a.w);
            u.z = pack2(c.x, c.y); u.w = pack2(c.z, c.w);
            *(uint4*)(&sK[0][row * 512 + ((d8 * 16) ^ ((row & 7) << 4))]) = u;
        }
#pragma unroll
        for (int i = 0; i < 2; ++i) {
            const int dv = i * 128 + tid;
            const uint rot = 4 * ((dv >> 1) & 15);
            const float* src = Vg + (size_t)b * LKg * DDg + dv;
            uchar* dst = &sV[0][dv * 64];
#pragma unroll
            for (int kq = 0; kq < 8; ++kq) {
                float v0 = src[(kq * 4 + 0) * DDg];
                float v1 = src[(kq * 4 + 1) * DDg];
                float v2 = src[(kq * 4 + 2) * DDg];
                float v3 = src[(kq * 4 + 3) * DDg];
                const uint o = (8 * kq + rot) & 63;
                *(uint*)(dst + o) = pack2(v0, v1);
                *(uint*)(dst + ((o + 4) & 63)) = pack2(v2, v3);
            }
        }
    }

    f32x16 acc[8];
#pragma unroll
    for (int i = 0; i < 8; ++i)
#pragma unroll
        for (int j = 0; j < 16; ++j) acc[i][j] = 0.f;

    float m = -1e30f, ell = 0.f;

    __syncthreads();   // drains vmcnt (gl_lds) + lds writes

    for (int t = 0; t < nt; ++t) {
        const int k0 = t * KVB;

        // ---- prefetch next tile into the other buffer ----
        if (t + 1 < nt) {
            if (IMG) {
                const uchar* gK = Kimg + (((size_t)(b * NTILES + t + 1)) << 14) + tid * 16;
                const uchar* gV = Vimg + (((size_t)(b * NTILES + t + 1)) << 14) + tid * 16;
#pragma unroll
                for (int i = 0; i < 8; ++i) {
                    gl_lds16(gK + i * 2048, &sK[cur ^ 1][i * 2048 + tid * 16]);
                    gl_lds16(gV + i * 2048, &sV[cur ^ 1][i * 2048 + tid * 16]);
                }
            } else {
                const int k1 = (t + 1) * KVB;
#pragma unroll
                for (int i = 0; i < 8; ++i) {
                    const int cid = i * 128 + tid;
                    const int d8 = cid & 31, row = cid >> 5;
                    const float* src = Kg + (((size_t)b * LKg + k1 + row) * DDg + d8 * 8);
                    float4 a = *(const float4*)src;
                    float4 c = *(const float4*)(src + 4);
                    uint4 u;
                    u.x = pack2(a.x, a.y); u.y = pack2(a.z, a.w);
                    u.z = pack2(c.x, c.y); u.w = pack2(c.z, c.w);
                    *(uint4*)(&sK[cur ^ 1][row * 512 + ((d8 * 16) ^ ((row & 7) << 4))]) = u;
                }
#pragma unroll
                for (int i = 0; i < 2; ++i) {
                    const int dv = i * 128 + tid;
                    const uint rot = 4 * ((dv >> 1) & 15);
                    const float* src = Vg + ((size_t)b * LKg + k1) * DDg + dv;
                    uchar* dst = &sV[cur ^ 1][dv * 64];
#pragma unroll
                    for (int kq = 0; kq < 8; ++kq) {
                        float v0 = src[(kq * 4 + 0) * DDg];
                        float v1 = src[(kq * 4 + 1) * DDg];
                        float v2 = src[(kq * 4 + 2) * DDg];
                        float v3 = src[(kq * 4 + 3) * DDg];
                        const uint o = (8 * kq + rot) & 63;
                        *(uint*)(dst + o) = pack2(v0, v1);
                        *(uint*)(dst + ((o + 4) & 63)) = pack2(v2, v3);
                    }
                }
            }
        }

        // ---- QK^T as S^T = mfma(K, Q^T): pair (l, l+32) holds P-row for q ----
        const uchar* sKc = sK[cur];
        const uchar* sVc = sV[cur];
        f32x16 s0;
#pragma unroll
        for (int j = 0; j < 16; ++j) s0[j] = 0.f;
#pragma unroll
        for (int c = 0; c < 16; ++c) {
            bf16x8 kf = *(const bf16x8*)(sKc + lq * 512 + ((c * 32 + h * 16) ^ swzK));
            s0 = mfma32(kf, qf[c], s0);
        }

        // ---- mask (masked score := 0, matching the reference) ----
        if (k0 + KVB > vl) {
            const int kb0 = k0 + 4 * h;
#pragma unroll
            for (int r = 0; r < 16; ++r) {
                const int key0 = kb0 + (r & 3) + 8 * (r >> 2);
                if (key0 >= vl) s0[r] = 0.f;
            }
        }

        // ---- online softmax; pair-consistent m/ell ----
        float mt = s0[0];
#pragma unroll
        for (int r = 1; r < 16; ++r) mt = fmaxf(mt, s0[r]);
        mt = fmaxf(mt, __shfl_xor(mt, 32));
        if (mt > m + 8.f) {
            const float mn = fmaxf(m, mt);
            const float sf = exp2f(m - mn);
            ell *= sf;
#pragma unroll
            for (int i = 0; i < 8; ++i) acc[i] *= sf;
            m = mn;
        }
        float rs = 0.f;
#pragma unroll
        for (int r = 0; r < 16; ++r) { s0[r] = exp2f(s0[r] - m); rs += s0[r]; }
        rs += __shfl_xor(rs, 32);
        ell += rs;

        // ---- build P^T B-fragments (half-exchange via shfl_xor 32) ----
        bf16x8 pf[2];
#pragma unroll
        for (int kc = 0; kc < 2; ++kc) {
            const int bb = kc * 8;
            uint w0 = pack2(s0[bb + 0], s0[bb + 1]);
            uint w1 = pack2(s0[bb + 2], s0[bb + 3]);
            uint w2 = pack2(s0[bb + 4], s0[bb + 5]);
            uint w3 = pack2(s0[bb + 6], s0[bb + 7]);
            uint e0 = __shfl_xor(w0, 32);
            uint e1 = __shfl_xor(w1, 32);
            uint e2 = __shfl_xor(w2, 32);
            uint e3 = __shfl_xor(w3, 32);
            uint4 u;
            u.x = h ? e2 : w0;
            u.y = h ? e3 : w1;
            u.z = h ? w2 : e0;
            u.w = h ? w3 : e1;
            pf[kc] = __builtin_bit_cast(bf16x8, u);
        }

        // ---- PV: O^T += mfma(V^T, P^T) ----
        // FIX(r5): writer wraps each DWORD independently within the 64B row;
        // read 4 x b32 with the same per-dword wrap (uint2 at offset 60 crossed
        // into the next dv row -> round-4 absmax 0.22). Banks: pos=(kk/2+(dv>>1))&15
        // -> all-distinct within h-group, 2-way across = free.
#pragma unroll
        for (int kc = 0; kc < 2; ++kc) {
            const int kk = kc * 16 + h * 8;
            const uint o0 = (uint)((2 * kk + rotv) & 63);
            const uint o1 = (uint)((2 * kk + 4 + rotv) & 63);
            const uint o2 = (uint)((2 * kk + 8 + rotv) & 63);
            const uint o3 = (uint)((2 * kk + 12 + rotv) & 63);
#pragma unroll
            for (int dt = 0; dt < 8; ++dt) {
                const uchar* base = sVc + dt * 2048 + lq * 64;
                uint4 u;
                u.x = *(const uint*)(base + o0);
                u.y = *(const uint*)(base + o1);
                u.z = *(const uint*)(base + o2);
                u.w = *(const uint*)(base + o3);
                acc[dt] = mfma32(__builtin_bit_cast(bf16x8, u), pf[kc], acc[dt]);
            }
        }

        __syncthreads();   // implicit vmcnt(0): next tile staged; reads of cur done
        cur ^= 1;
    }

    // ---- analytic masked tail: scores are exactly 0 there ----
    if (use_tail) {
        const int bnd = nt * KVB;
        const int cnt = LKg - bnd;
        if (cnt > 0) {
            if (m < -8.f) {
                const float sf = exp2f(m);
                ell *= sf;
#pragma unroll
                for (int i = 0; i < 8; ++i) acc[i] *= sf;
                m = 0.f;
            }
            const float pt = exp2f(-m);
            ell += (float)cnt * pt;
            const float* tp = TV + b * DDg + h * 4;
#pragma unroll
            for (int dt = 0; dt < 8; ++dt) {
#pragma unroll
                for (int rg = 0; rg < 4; ++rg) {
                    float4 tv = *(const float4*)(tp + dt * 32 + rg * 8);
                    acc[dt][rg * 4 + 0] += pt * tv.x;
                    acc[dt][rg * 4 + 1] += pt * tv.y;
                    acc[dt][rg * 4 + 2] += pt * tv.z;
                    acc[dt][rg * 4 + 3] += pt * tv.w;
                }
            }
        }
    }

    // ---- epilogue: O = O^T(lane-local column) / ell ----
    const float inv = 1.f / ell;
    float* op = Og + ((size_t)(b * LQg + q)) * DDg + h * 4;
#pragma unroll
    for (int dt = 0; dt < 8; ++dt) {
#pragma unroll
        for (int rg = 0; rg < 4; ++rg) {
            float4 o;
            o.x = acc[dt][rg * 4 + 0] * inv;
            o.y = acc[dt][rg * 4 + 1] * inv;
            o.z = acc[dt][rg * 4 + 2] * inv;
            o.w = acc[dt][rg * 4 + 3] * inv;
            *(float4*)(op + dt * 32 + rg * 8) = o;
        }
    }
}

extern "C" void kernel_launch(void* const* d_in, const int* in_sizes, int n_in,
                              void* d_out, int out_size, void* d_ws, size_t ws_size,
                              hipStream_t stream) {
    const float* Q = (const float*)d_in[0];
    const float* K = (const float*)d_in[1];
    const float* V = (const float*)d_in[2];
    const int* vlen = (const int*)d_in[3];
    float* out = (float*)d_out;

    // ws layout: part(256KB) | TV(16KB) | Kimg(16MB) | Vimg(16MB)
    const size_t off_part = 0;
    const size_t off_TV = 262144;
    const size_t off_K = 524288;
    const size_t imgsz = (size_t)NBg * NTILES * 16384;   // 16 MB
    const size_t off_V = off_K + imgsz;
    const size_t need_tail = off_TV + (size_t)NBg * DDg * 4;
    const size_t need_img = off_V + imgsz;

    const int use_tail = (ws_size >= need_tail) ? 1 : 0;
    const int use_img = (ws_size >= need_img) ? 1 : 0;

    float* part = (float*)((char*)d_ws + off_part);
    float* TV = (float*)((char*)d_ws + off_TV);
    uchar* Kimg = (uchar*)d_ws + off_K;
    uchar* Vimg = (uchar*)d_ws + off_V;

    if (use_tail) {
        tv_partial_k<<<dim3(16, 16), 256, 0, stream>>>(V, vlen, part);
        tv_reduce_k<<<dim3(16), 256, 0, stream>>>(part, TV);
    }
    if (use_img) {
        prep_k<<<dim3(4096), 256, 0, stream>>>(K, Kimg);
        prep_v<<<dim3(1024), 256, 0, stream>>>(V, Vimg);
        attn_k<1><<<dim3(512), 128, 0, stream>>>(Q, K, V, Kimg, Vimg, vlen, TV, out, use_tail);
    } else {
        attn_k<0><<<dim3(512), 128, 0, stream>>>(Q, K, V, Kimg, Vimg, vlen, TV, out, use_tail);
    }
}